// Round 8
// baseline (7176.892 us; speedup 1.0000x reference)
//
#include <hip/hip_runtime.h>
#include <hip/hip_fp16.h>
#include <hip/hip_cooperative_groups.h>

namespace cg = cooperative_groups;

// Entropic OT (Sinkhorn), B=64, n=m=1024, d=64, eps=0.1, 50 iters.
// q[b,i,j] = <s_i,t_j> (unit rows) stored once as fp16 (128 MiB).
// cost = 2-2q exactly. u = 2^{CK q}; row: s_i = sum_j u*wv_j, g = 2^-10/s_i;
// col partial: acc_j += u*g; next pass wv_j = 2^-10 / colsum_j.
//
// R8 = R7 re-submission (GPU never acquired). Audit notes:
//  * coop de-risked: 512 blocks (2/CU), occupancy-query + rc-checked,
//    guaranteed fallback = 50 single-pass launches of the same body.
//  * BARRIER-FREE pipeline: each wave stages & reads only its own tile row
//    (hazards wave-private, enforced by counted vmcnt): 4-row tiles, 4 LDS
//    buffers, 3-deep prefetch, {stage(t+3); vmcnt(6); compute(t)}; tail 4/2/0.
//  * Bank fix: lane owns cols {8L..8L+7} u {512+8L..+7} (16B/lane reads).

#define BATCH  64
#define NPT    1024
#define DIM    64
#define NCHUNK 8                      // blocks per batch; 128 rows each
#define NBLK   (BATCH * NCHUNK)      // 512
#define CKF    28.853900817779268f   // 20 * log2(e)
#define WV0F   2.0611536224e-9f      // 2^{-CK} = e^-20 (lv=0 first pass)
#define G10F   0.0009765625f         // 2^{-10}

#if __has_builtin(__builtin_amdgcn_exp2f)
#define EXP2F(x) __builtin_amdgcn_exp2f(x)
#else
#define EXP2F(x) exp2f(x)
#endif

__device__ __forceinline__ float2 h2tof2(unsigned int u) {
  return __half22float2(__builtin_bit_cast(__half2, u));
}
__device__ __forceinline__ void dec8(uint4 pk, float* f) {
  float2 t;
  t = h2tof2(pk.x); f[0] = t.x; f[1] = t.y;
  t = h2tof2(pk.y); f[2] = t.x; f[3] = t.y;
  t = h2tof2(pk.z); f[4] = t.x; f[5] = t.y;
  t = h2tof2(pk.w); f[6] = t.x; f[7] = t.y;
}
__device__ __forceinline__ void stage16(const __half* g, __half* l) {
  __builtin_amdgcn_global_load_lds(
      (const __attribute__((address_space(1))) void*)g,
      (__attribute__((address_space(3))) void*)l, 16, 0, 0);
}

// ---------------------------------------------------------------------------
// build_q: per-batch GEMM dot[i,j] = <s_i/|s_i|, t_j/|t_j|>, fp16 out. 148us.
// ---------------------------------------------------------------------------
__global__ __launch_bounds__(256) void build_q(
    const float* __restrict__ src, const float* __restrict__ tgt,
    __half* __restrict__ q)
{
  __shared__ float sA[DIM][68];
  __shared__ float sB[DIM][68];

  const int b    = blockIdx.x >> 8;
  const int tile = blockIdx.x & 255;
  const int i0 = (tile >> 4) << 6;
  const int j0 = (tile & 15) << 6;
  const int tid = threadIdx.x;
  const int r = tid >> 2;
  const int c = tid & 3;

  {
    const float4* p4 = (const float4*)(src + ((size_t)b * NPT + (i0 + r)) * DIM + c * 16);
    float4 a0 = p4[0], a1 = p4[1], a2 = p4[2], a3 = p4[3];
    float v[16] = {a0.x,a0.y,a0.z,a0.w, a1.x,a1.y,a1.z,a1.w,
                   a2.x,a2.y,a2.z,a2.w, a3.x,a3.y,a3.z,a3.w};
    float ss = 0.f;
    #pragma unroll
    for (int k = 0; k < 16; ++k) ss = fmaf(v[k], v[k], ss);
    ss += __shfl_xor(ss, 1);
    ss += __shfl_xor(ss, 2);
    const float sc = 1.0f / fmaxf(sqrtf(ss), 1e-12f);
    #pragma unroll
    for (int k = 0; k < 16; ++k) sA[c * 16 + k][r] = v[k] * sc;
  }
  {
    const float4* p4 = (const float4*)(tgt + ((size_t)b * NPT + (j0 + r)) * DIM + c * 16);
    float4 a0 = p4[0], a1 = p4[1], a2 = p4[2], a3 = p4[3];
    float v[16] = {a0.x,a0.y,a0.z,a0.w, a1.x,a1.y,a1.z,a1.w,
                   a2.x,a2.y,a2.z,a2.w, a3.x,a3.y,a3.z,a3.w};
    float ss = 0.f;
    #pragma unroll
    for (int k = 0; k < 16; ++k) ss = fmaf(v[k], v[k], ss);
    ss += __shfl_xor(ss, 1);
    ss += __shfl_xor(ss, 2);
    const float sc = 1.0f / fmaxf(sqrtf(ss), 1e-12f);
    #pragma unroll
    for (int k = 0; k < 16; ++k) sB[c * 16 + k][r] = v[k] * sc;
  }
  __syncthreads();

  const int mi = (tid >> 4) << 2;
  const int mj = (tid & 15) << 2;
  float acc[4][4] = {};
  #pragma unroll 16
  for (int d = 0; d < DIM; ++d) {
    const float4 a = *(const float4*)&sA[d][mi];
    const float4 t = *(const float4*)&sB[d][mj];
    const float av[4] = {a.x, a.y, a.z, a.w};
    const float tv[4] = {t.x, t.y, t.z, t.w};
    #pragma unroll
    for (int ii = 0; ii < 4; ++ii)
      #pragma unroll
      for (int jj = 0; jj < 4; ++jj)
        acc[ii][jj] = fmaf(av[ii], tv[jj], acc[ii][jj]);
  }

  #pragma unroll
  for (int ii = 0; ii < 4; ++ii) {
    __half2 h0 = __floats2half2_rn(acc[ii][0], acc[ii][1]);
    __half2 h1 = __floats2half2_rn(acc[ii][2], acc[ii][3]);
    uint2 pk = { __builtin_bit_cast(unsigned int, h0),
                 __builtin_bit_cast(unsigned int, h1) };
    *(uint2*)(q + (size_t)b * NPT * NPT
                + (size_t)(i0 + mi + ii) * NPT + (j0 + mj)) = pk;
  }
}

// ---------------------------------------------------------------------------
// pass_once: one full Sinkhorn iteration over this block's 128-row slab.
// Wave w stages & computes row w of each 4-row tile (hazards wave-private).
// ---------------------------------------------------------------------------
template<bool FIRST, bool FIN>
__device__ __forceinline__ void pass_once(
    const __half* __restrict__ qt,     // block's 128-row slab base
    const float* __restrict__ pR, float* __restrict__ pW,
    float* __restrict__ cpart,
    __half (*smem)[4][NPT],            // [4 buffers][4 rows][NPT]
    const int b, const int chunk, const int lane, const int wave, const int tid)
{
  const int lhalf = lane << 3;         // 8-elem offset inside a 512 block

  // stage tiles 0,1,2 (3-deep pipeline prologue)
  {
    const __half* g0 = qt + (wave << 10) + lhalf;
    #pragma unroll
    for (int tt = 0; tt < 3; ++tt) {
      __half* l = &smem[tt][wave][0] + lhalf;
      stage16(g0 + (tt << 12), l);
      stage16(g0 + (tt << 12) + 512, l + 512);
    }
  }

  // wv[k] = 2^{lv_j - CK} = 2^-10 / colsum_j for this lane's 16 cols
  // (cols {8L..8L+7} for k<8, {512+8L..} for k>=8)
  float wv[16];
  if (FIRST) {
    #pragma unroll
    for (int k = 0; k < 16; ++k) wv[k] = WV0F;
  } else {
    float sv[16] = {};
    #pragma unroll
    for (int s = 0; s < NCHUNK; ++s) {
      const float* base = pR + ((size_t)((s << 6) + b) << 10);
      const float4* pa = (const float4*)(base + lhalf);
      const float4* pb = (const float4*)(base + 512 + lhalf);
      const float4 v0 = pa[0], v1 = pa[1], v2 = pb[0], v3 = pb[1];
      sv[0] += v0.x;  sv[1] += v0.y;  sv[2]  += v0.z;  sv[3]  += v0.w;
      sv[4] += v1.x;  sv[5] += v1.y;  sv[6]  += v1.z;  sv[7]  += v1.w;
      sv[8] += v2.x;  sv[9] += v2.y;  sv[10] += v2.z;  sv[11] += v2.w;
      sv[12] += v3.x; sv[13] += v3.y; sv[14] += v3.z;  sv[15] += v3.w;
    }
    #pragma unroll
    for (int k = 0; k < 16; ++k) wv[k] = G10F / sv[k];
  }

  float acc[16] = {};
  float cacc[16] = {};

  #pragma unroll 4
  for (int t = 0; t < 32; ++t) {
    // issue next prefetch BEFORE stalling (keeps 3 tiles in flight)
    if (t + 3 < 32) {
      const __half* gs = qt + ((size_t)(t + 3) << 12) + (wave << 10) + lhalf;
      __half* ls = &smem[(t + 3) & 3][wave][0] + lhalf;
      stage16(gs, ls);
      stage16(gs + 512, ls + 512);
    }
    const int rem = 31 - t;
    if (rem >= 3)      asm volatile("s_waitcnt vmcnt(6)" ::: "memory");
    else if (rem == 2) asm volatile("s_waitcnt vmcnt(4)" ::: "memory");
    else if (rem == 1) asm volatile("s_waitcnt vmcnt(2)" ::: "memory");
    else               asm volatile("s_waitcnt vmcnt(0)" ::: "memory");

    // compute tile t, row `wave` (the row this wave staged itself)
    const __half* row = &smem[t & 3][wave][0];
    const uint4 pa = *(const uint4*)(row + lhalf);
    const uint4 pb = *(const uint4*)(row + 512 + lhalf);
    float f[16];
    dec8(pa, f);
    dec8(pb, f + 8);
    float u[16];
    #pragma unroll
    for (int k = 0; k < 16; ++k) u[k] = EXP2F(f[k] * CKF);

    float d0 = 0.f, d1 = 0.f, d2 = 0.f, d3 = 0.f;
    #pragma unroll
    for (int k = 0; k < 16; k += 4) {
      d0 = fmaf(u[k],     wv[k],     d0);
      d1 = fmaf(u[k + 1], wv[k + 1], d1);
      d2 = fmaf(u[k + 2], wv[k + 2], d2);
      d3 = fmaf(u[k + 3], wv[k + 3], d3);
    }
    float s = (d0 + d1) + (d2 + d3);
    #pragma unroll
    for (int m = 1; m <= 32; m <<= 1) s += __shfl_xor(s, m);
    const float g = G10F / s;   // 2^{lu_i}

    #pragma unroll
    for (int k = 0; k < 16; ++k) acc[k] = fmaf(u[k], g, acc[k]);
    if (FIN) {
      #pragma unroll
      for (int k = 0; k < 16; ++k)
        cacc[k] = fmaf(u[k] * g, fmaf(f[k], -2.0f, 2.0f), cacc[k]);
    }
  }

  // epilogue: cross-wave combine in LDS, one coalesced 4KB store per block
  __syncthreads();
  float* lp = (float*)&smem[0][0][0];   // 16 KB (buffers 0-1)
  float* lc = (float*)&smem[2][0][0];   // 16 KB (buffers 2-3, FIN only)
  {
    float* lpw = lp + (wave << 10);
    *(float4*)(lpw + lhalf)       = make_float4(acc[0], acc[1], acc[2], acc[3]);
    *(float4*)(lpw + lhalf + 4)   = make_float4(acc[4], acc[5], acc[6], acc[7]);
    *(float4*)(lpw + 512 + lhalf) = make_float4(acc[8], acc[9], acc[10], acc[11]);
    *(float4*)(lpw + 516 + lhalf) = make_float4(acc[12], acc[13], acc[14], acc[15]);
    if (FIN) {
      float* lcw = lc + (wave << 10);
      *(float4*)(lcw + lhalf)       = make_float4(cacc[0], cacc[1], cacc[2], cacc[3]);
      *(float4*)(lcw + lhalf + 4)   = make_float4(cacc[4], cacc[5], cacc[6], cacc[7]);
      *(float4*)(lcw + 512 + lhalf) = make_float4(cacc[8], cacc[9], cacc[10], cacc[11]);
      *(float4*)(lcw + 516 + lhalf) = make_float4(cacc[12], cacc[13], cacc[14], cacc[15]);
    }
  }
  __syncthreads();
  {
    const float4* lp4 = (const float4*)lp;
    const float4 p0 = lp4[tid], p1 = lp4[256 + tid],
                 p2 = lp4[512 + tid], p3 = lp4[768 + tid];
    float4 s4;
    s4.x = (p0.x + p1.x) + (p2.x + p3.x);
    s4.y = (p0.y + p1.y) + (p2.y + p3.y);
    s4.z = (p0.z + p1.z) + (p2.z + p3.z);
    s4.w = (p0.w + p1.w) + (p2.w + p3.w);
    ((float4*)(pW + ((size_t)((chunk << 6) + b) << 10)))[tid] = s4;
    if (FIN) {
      const float4* lc4 = (const float4*)lc;
      const float4 c0 = lc4[tid], c1 = lc4[256 + tid],
                   c2 = lc4[512 + tid], c3 = lc4[768 + tid];
      float4 c4;
      c4.x = (c0.x + c1.x) + (c2.x + c3.x);
      c4.y = (c0.y + c1.y) + (c2.y + c3.y);
      c4.z = (c0.z + c1.z) + (c2.z + c3.z);
      c4.w = (c0.w + c1.w) + (c2.w + c3.w);
      ((float4*)(cpart + ((size_t)((chunk << 6) + b) << 10)))[tid] = c4;
    }
  }
}

// ---------------------------------------------------------------------------
// coop_sink: all 50 passes + final reduce in one cooperative dispatch.
// 512 blocks x 256 thr (2 blocks/CU co-residency).
// ---------------------------------------------------------------------------
__global__ __launch_bounds__(256)
__attribute__((amdgpu_waves_per_eu(4, 4)))
void coop_sink(const __half* __restrict__ q,
               float* __restrict__ partA, float* __restrict__ partB,
               float* __restrict__ cpart, float* __restrict__ out)
{
  __shared__ __align__(16) __half smem[4][4][NPT];   // 32 KB

  const int b     = blockIdx.x >> 3;
  const int chunk = blockIdx.x & 7;
  const int lane  = threadIdx.x & 63;
  const int wave  = threadIdx.x >> 6;
  const int tid   = threadIdx.x;
  cg::grid_group grid = cg::this_grid();

  const __half* qt = q + ((size_t)b << 20) + ((size_t)(chunk << 7) << 10);

  for (int pass = 0; pass < 50; ++pass) {
    const float* pR = (pass & 1) ? partB : partA;
    float*       pW = (pass & 1) ? partA : partB;
    if (pass == 0)
      pass_once<true, false>(qt, pR, pW, cpart, smem, b, chunk, lane, wave, tid);
    else if (pass < 49)
      pass_once<false, false>(qt, pR, pW, cpart, smem, b, chunk, lane, wave, tid);
    else
      pass_once<false, true>(qt, pR, pW, cpart, smem, b, chunk, lane, wave, tid);
    __threadfence();
    grid.sync();
  }

  // final reduce: one block per batch (chunk==0). pass 49 wrote partA.
  if (chunk == 0) {
    float4 p = {0.f, 0.f, 0.f, 0.f}, c = {0.f, 0.f, 0.f, 0.f};
    #pragma unroll
    for (int s = 0; s < NCHUNK; ++s) {
      const size_t base = (size_t)((s << 6) + b) << 8;
      const float4 pv = ((const float4*)partA)[base + tid];
      const float4 cv = ((const float4*)cpart)[base + tid];
      p.x += pv.x; p.y += pv.y; p.z += pv.z; p.w += pv.w;
      c.x += cv.x; c.y += cv.y; c.z += cv.z; c.w += cv.w;
    }
    float r = (c.x / p.x + c.y / p.y) + (c.z / p.z + c.w / p.w);
    #pragma unroll
    for (int m = 1; m <= 32; m <<= 1) r += __shfl_xor(r, m);
    float* lsf = (float*)&smem[0][0][0];
    if (lane == 0) lsf[wave] = r;
    __syncthreads();
    if (tid == 0)
      atomicAdd(out, (lsf[0] + lsf[1] + lsf[2] + lsf[3]) * (1.0f / 65536.0f));
  }
}

// ---------------------------------------------------------------------------
// Fallback path: one pass per launch (same body), then a reduce kernel.
// ---------------------------------------------------------------------------
template<bool FIRST, bool FIN>
__global__ __launch_bounds__(256)
__attribute__((amdgpu_waves_per_eu(4, 4)))
void sink_fb(const __half* __restrict__ q, const float* __restrict__ pR,
             float* __restrict__ pW, float* __restrict__ cpart)
{
  __shared__ __align__(16) __half smem[4][4][NPT];
  const int b     = blockIdx.x >> 3;
  const int chunk = blockIdx.x & 7;
  const __half* qt = q + ((size_t)b << 20) + ((size_t)(chunk << 7) << 10);
  pass_once<FIRST, FIN>(qt, pR, pW, cpart, smem, b, chunk,
                        threadIdx.x & 63, threadIdx.x >> 6, threadIdx.x);
}

__global__ __launch_bounds__(256) void final_fb(
    const float* __restrict__ partA, const float* __restrict__ cpart,
    float* __restrict__ out)
{
  const int b   = blockIdx.x;
  const int tid = threadIdx.x;
  float4 p = {0.f, 0.f, 0.f, 0.f}, c = {0.f, 0.f, 0.f, 0.f};
  #pragma unroll
  for (int s = 0; s < NCHUNK; ++s) {
    const size_t base = (size_t)((s << 6) + b) << 8;
    const float4 pv = ((const float4*)partA)[base + tid];
    const float4 cv = ((const float4*)cpart)[base + tid];
    p.x += pv.x; p.y += pv.y; p.z += pv.z; p.w += pv.w;
    c.x += cv.x; c.y += cv.y; c.z += cv.z; c.w += cv.w;
  }
  float r = (c.x / p.x + c.y / p.y) + (c.z / p.z + c.w / p.w);
  #pragma unroll
  for (int m = 1; m <= 32; m <<= 1) r += __shfl_xor(r, m);
  __shared__ float lsf[4];
  if ((tid & 63) == 0) lsf[tid >> 6] = r;
  __syncthreads();
  if (tid == 0)
    atomicAdd(out, (lsf[0] + lsf[1] + lsf[2] + lsf[3]) * (1.0f / 65536.0f));
}

// ---------------------------------------------------------------------------
extern "C" void kernel_launch(void* const* d_in, const int* in_sizes, int n_in,
                              void* d_out, int out_size, void* d_ws, size_t ws_size,
                              hipStream_t stream)
{
  (void)in_sizes; (void)n_in; (void)out_size; (void)ws_size;
  const float* src = (const float*)d_in[0];
  const float* tgt = (const float*)d_in[1];

  char* ws = (char*)d_ws;
  __half* q = (__half*)ws;                                    // 128 MiB
  const size_t QB = (size_t)BATCH * NPT * NPT * sizeof(__half);
  const size_t PART_N = (size_t)NCHUNK * BATCH * NPT;         // 2 MiB each
  float* partA = (float*)(ws + QB);
  float* partB = partA + PART_N;
  float* cpart = partB + PART_N;
  float* outp  = (float*)d_out;

  hipMemsetAsync(d_out, 0, sizeof(float), stream);

  build_q<<<BATCH * 256, 256, 0, stream>>>(src, tgt, q);

  // cooperative path if occupancy allows 512 co-resident blocks (2/CU)
  int maxb = 0;
  hipError_t qrc = hipOccupancyMaxActiveBlocksPerMultiprocessor(
      &maxb, coop_sink, 256, 0);
  hipError_t rc = hipErrorUnknown;
  if (qrc == hipSuccess && maxb >= 2) {
    const __half* qa = q;
    void* args[5] = {(void*)&qa, (void*)&partA, (void*)&partB,
                     (void*)&cpart, (void*)&outp};
    rc = hipLaunchCooperativeKernel((void*)coop_sink, dim3(NBLK), dim3(256),
                                    args, 0, stream);
  }
  if (rc != hipSuccess) {
    // guaranteed fallback: 50 single-pass launches of the same body
    for (int t = 0; t < 50; ++t) {
      const float* R = (t & 1) ? partB : partA;
      float*       W = (t & 1) ? partA : partB;
      if (t == 0)
        sink_fb<true, false><<<NBLK, 256, 0, stream>>>(q, R, W, cpart);
      else if (t == 49)
        sink_fb<false, true><<<NBLK, 256, 0, stream>>>(q, R, W, cpart);
      else
        sink_fb<false, false><<<NBLK, 256, 0, stream>>>(q, R, W, cpart);
    }
    final_fb<<<BATCH, 256, 0, stream>>>(partA, cpart, (float*)d_out);
  }
}

// Round 10
// 1952.139 us; speedup vs baseline: 3.6764x; 3.6764x over previous
//
#include <hip/hip_runtime.h>
#include <hip/hip_fp16.h>

// Entropic OT (Sinkhorn), B=64, n=m=1024, d=64, eps=0.1, 50 iters.
// q[b,i,j] = <s_i,t_j> (unit rows) stored once as fp16 (128 MiB).
// cost = 2-2q exactly. u = 2^{CK q}; row: s_i = sum_j u*wv_j, g = 2^-10/s_i;
// col partial: acc_j += u*g; next pass wv_j = 2^-10 / colsum_j.
//
// R10 = R9 re-submission (GPU never acquired; audit found no defects).
//  * R5's PROVEN structure (separate launches, syncthreads double-buffer),
//    2x TLP: 2048 blocks (32-row slabs), 16 KB LDS -> 8 blocks/CU = 32
//    waves/CU cap (R5: 4 blocks/CU at 38us/pass).
//  * per-pass colsum_wv kernel (64 blocks) pre-reduces slab partials and
//    emits wv_j directly; sink prologue = one 64B/thread load.
//  * pipeline per pass: 8 rounds of 4-row tiles; wave w stages & computes
//    row w; {sync; stage(t+1); compute(t)}; LDS-overlay epilogue, no atomics.

#define BATCH  64
#define NPT    1024
#define DIM    64
#define NCHUNK 32                    // blocks per batch; 32 rows each
#define NBLK   (BATCH * NCHUNK)      // 2048
#define CKF    28.853900817779268f   // 20 * log2(e)
#define WV0F   2.0611536224e-9f      // 2^{-CK} = e^-20 (lv=0 first pass)
#define G10F   0.0009765625f         // 2^{-10}

#if __has_builtin(__builtin_amdgcn_exp2f)
#define EXP2F(x) __builtin_amdgcn_exp2f(x)
#else
#define EXP2F(x) exp2f(x)
#endif

__device__ __forceinline__ float2 h2tof2(unsigned int u) {
  return __half22float2(__builtin_bit_cast(__half2, u));
}
__device__ __forceinline__ void dec8(uint4 pk, float* f) {
  float2 t;
  t = h2tof2(pk.x); f[0] = t.x; f[1] = t.y;
  t = h2tof2(pk.y); f[2] = t.x; f[3] = t.y;
  t = h2tof2(pk.z); f[4] = t.x; f[5] = t.y;
  t = h2tof2(pk.w); f[6] = t.x; f[7] = t.y;
}
__device__ __forceinline__ void stage16(const __half* g, __half* l) {
  __builtin_amdgcn_global_load_lds(
      (const __attribute__((address_space(1))) void*)g,
      (__attribute__((address_space(3))) void*)l, 16, 0, 0);
}

// ---------------------------------------------------------------------------
// build_q: per-batch GEMM dot[i,j] = <s_i/|s_i|, t_j/|t_j|>, fp16 out. 148us.
// ---------------------------------------------------------------------------
__global__ __launch_bounds__(256) void build_q(
    const float* __restrict__ src, const float* __restrict__ tgt,
    __half* __restrict__ q)
{
  __shared__ float sA[DIM][68];
  __shared__ float sB[DIM][68];

  const int b    = blockIdx.x >> 8;
  const int tile = blockIdx.x & 255;
  const int i0 = (tile >> 4) << 6;
  const int j0 = (tile & 15) << 6;
  const int tid = threadIdx.x;
  const int r = tid >> 2;
  const int c = tid & 3;

  {
    const float4* p4 = (const float4*)(src + ((size_t)b * NPT + (i0 + r)) * DIM + c * 16);
    float4 a0 = p4[0], a1 = p4[1], a2 = p4[2], a3 = p4[3];
    float v[16] = {a0.x,a0.y,a0.z,a0.w, a1.x,a1.y,a1.z,a1.w,
                   a2.x,a2.y,a2.z,a2.w, a3.x,a3.y,a3.z,a3.w};
    float ss = 0.f;
    #pragma unroll
    for (int k = 0; k < 16; ++k) ss = fmaf(v[k], v[k], ss);
    ss += __shfl_xor(ss, 1);
    ss += __shfl_xor(ss, 2);
    const float sc = 1.0f / fmaxf(sqrtf(ss), 1e-12f);
    #pragma unroll
    for (int k = 0; k < 16; ++k) sA[c * 16 + k][r] = v[k] * sc;
  }
  {
    const float4* p4 = (const float4*)(tgt + ((size_t)b * NPT + (j0 + r)) * DIM + c * 16);
    float4 a0 = p4[0], a1 = p4[1], a2 = p4[2], a3 = p4[3];
    float v[16] = {a0.x,a0.y,a0.z,a0.w, a1.x,a1.y,a1.z,a1.w,
                   a2.x,a2.y,a2.z,a2.w, a3.x,a3.y,a3.z,a3.w};
    float ss = 0.f;
    #pragma unroll
    for (int k = 0; k < 16; ++k) ss = fmaf(v[k], v[k], ss);
    ss += __shfl_xor(ss, 1);
    ss += __shfl_xor(ss, 2);
    const float sc = 1.0f / fmaxf(sqrtf(ss), 1e-12f);
    #pragma unroll
    for (int k = 0; k < 16; ++k) sB[c * 16 + k][r] = v[k] * sc;
  }
  __syncthreads();

  const int mi = (tid >> 4) << 2;
  const int mj = (tid & 15) << 2;
  float acc[4][4] = {};
  #pragma unroll 16
  for (int d = 0; d < DIM; ++d) {
    const float4 a = *(const float4*)&sA[d][mi];
    const float4 t = *(const float4*)&sB[d][mj];
    const float av[4] = {a.x, a.y, a.z, a.w};
    const float tv[4] = {t.x, t.y, t.z, t.w};
    #pragma unroll
    for (int ii = 0; ii < 4; ++ii)
      #pragma unroll
      for (int jj = 0; jj < 4; ++jj)
        acc[ii][jj] = fmaf(av[ii], tv[jj], acc[ii][jj]);
  }

  #pragma unroll
  for (int ii = 0; ii < 4; ++ii) {
    __half2 h0 = __floats2half2_rn(acc[ii][0], acc[ii][1]);
    __half2 h1 = __floats2half2_rn(acc[ii][2], acc[ii][3]);
    uint2 pk = { __builtin_bit_cast(unsigned int, h0),
                 __builtin_bit_cast(unsigned int, h1) };
    *(uint2*)(q + (size_t)b * NPT * NPT
                + (size_t)(i0 + mi + ii) * NPT + (j0 + mj)) = pk;
  }
}

// ---------------------------------------------------------------------------
// sink_pass<FIRST,FIN>: one Sinkhorn iteration over a 32-row slab.
// Grid 2048 x 256. Wave w stages & computes row w of each 4-row tile.
// Lane owns cols {8L..8L+7} u {512+8L..512+8L+7}.
// ---------------------------------------------------------------------------
template<bool FIRST, bool FIN>
__global__ __launch_bounds__(256) void sink_pass(
    const __half* __restrict__ q,
    const float* __restrict__ colwv,  // [BATCH][NPT]: wv_j (pass>0)
    float* __restrict__ part,         // [NCHUNK][BATCH][NPT] colsum partials
    float* __restrict__ cpart)        // cost partials (FIN only)
{
  __shared__ __align__(16) __half smem[2][4][NPT];   // 16 KB

  const int b     = blockIdx.x >> 5;
  const int chunk = blockIdx.x & 31;
  const int lane  = threadIdx.x & 63;
  const int wave  = threadIdx.x >> 6;
  const int tid   = threadIdx.x;
  const int lhalf = lane << 3;

  const __half* qt = q + ((size_t)b << 20) + ((size_t)(chunk << 5) << 10);

  // stage tile 0 (wave w -> row w; 2x 1KB halves; latency hides under wv load)
  {
    const __half* g0 = qt + (wave << 10) + lhalf;
    __half* l0 = &smem[0][wave][0] + lhalf;
    stage16(g0, l0);
    stage16(g0 + 512, l0 + 512);
  }

  float wv[16];
  if (FIRST) {
    #pragma unroll
    for (int k = 0; k < 16; ++k) wv[k] = WV0F;
  } else {
    const float4* wp = (const float4*)(colwv + ((size_t)b << 10) + lhalf);
    const float4 w0 = wp[0], w1 = wp[1];
    const float4 w2 = ((const float4*)(colwv + ((size_t)b << 10) + 512 + lhalf))[0];
    const float4 w3 = ((const float4*)(colwv + ((size_t)b << 10) + 512 + lhalf))[1];
    wv[0] = w0.x;  wv[1] = w0.y;  wv[2]  = w0.z;  wv[3]  = w0.w;
    wv[4] = w1.x;  wv[5] = w1.y;  wv[6]  = w1.z;  wv[7]  = w1.w;
    wv[8] = w2.x;  wv[9] = w2.y;  wv[10] = w2.z;  wv[11] = w2.w;
    wv[12] = w3.x; wv[13] = w3.y; wv[14] = w3.z;  wv[15] = w3.w;
  }

  float acc[16] = {};
  float cacc[16] = {};

  #pragma unroll
  for (int t = 0; t < 8; ++t) {
    __syncthreads();   // implicit vmcnt(0): tile t landed; buffers swappable
    if (t < 7) {       // stage tile t+1 (in flight during compute of t)
      const __half* gs = qt + ((size_t)(((t + 1) << 2) + wave) << 10) + lhalf;
      __half* ls = &smem[(t + 1) & 1][wave][0] + lhalf;
      stage16(gs, ls);
      stage16(gs + 512, ls + 512);
    }
    const __half* row = &smem[t & 1][wave][0];
    const uint4 pa = *(const uint4*)(row + lhalf);
    const uint4 pb = *(const uint4*)(row + 512 + lhalf);
    float f[16];
    dec8(pa, f);
    dec8(pb, f + 8);
    float u[16];
    #pragma unroll
    for (int k = 0; k < 16; ++k) u[k] = EXP2F(f[k] * CKF);

    float d0 = 0.f, d1 = 0.f, d2 = 0.f, d3 = 0.f;
    #pragma unroll
    for (int k = 0; k < 16; k += 4) {
      d0 = fmaf(u[k],     wv[k],     d0);
      d1 = fmaf(u[k + 1], wv[k + 1], d1);
      d2 = fmaf(u[k + 2], wv[k + 2], d2);
      d3 = fmaf(u[k + 3], wv[k + 3], d3);
    }
    float s = (d0 + d1) + (d2 + d3);
    #pragma unroll
    for (int m = 1; m <= 32; m <<= 1) s += __shfl_xor(s, m);
    const float g = G10F / s;   // 2^{lu_i}

    #pragma unroll
    for (int k = 0; k < 16; ++k) acc[k] = fmaf(u[k], g, acc[k]);
    if (FIN) {
      #pragma unroll
      for (int k = 0; k < 16; ++k)
        cacc[k] = fmaf(u[k] * g, fmaf(f[k], -2.0f, 2.0f), cacc[k]);
    }
  }

  // epilogue: cross-wave combine in LDS overlay, one 4KB store per block
  __syncthreads();
  float* lp = (float*)&smem[0][0][0];   // [4][1024] floats = 16 KB
  {
    float* lpw = lp + (wave << 10);
    *(float4*)(lpw + lhalf)       = make_float4(acc[0], acc[1], acc[2], acc[3]);
    *(float4*)(lpw + lhalf + 4)   = make_float4(acc[4], acc[5], acc[6], acc[7]);
    *(float4*)(lpw + 512 + lhalf) = make_float4(acc[8], acc[9], acc[10], acc[11]);
    *(float4*)(lpw + 516 + lhalf) = make_float4(acc[12], acc[13], acc[14], acc[15]);
  }
  __syncthreads();
  {
    const float4* lp4 = (const float4*)lp;
    const float4 p0 = lp4[tid], p1 = lp4[256 + tid],
                 p2 = lp4[512 + tid], p3 = lp4[768 + tid];
    float4 s4;
    s4.x = (p0.x + p1.x) + (p2.x + p3.x);
    s4.y = (p0.y + p1.y) + (p2.y + p3.y);
    s4.z = (p0.z + p1.z) + (p2.z + p3.z);
    s4.w = (p0.w + p1.w) + (p2.w + p3.w);
    ((float4*)(part + ((size_t)((chunk << 6) + b) << 10)))[tid] = s4;
  }
  if (FIN) {   // second overlay round for cost partials (pass 49 only)
    __syncthreads();
    {
      float* lpw = lp + (wave << 10);
      *(float4*)(lpw + lhalf)       = make_float4(cacc[0], cacc[1], cacc[2], cacc[3]);
      *(float4*)(lpw + lhalf + 4)   = make_float4(cacc[4], cacc[5], cacc[6], cacc[7]);
      *(float4*)(lpw + 512 + lhalf) = make_float4(cacc[8], cacc[9], cacc[10], cacc[11]);
      *(float4*)(lpw + 516 + lhalf) = make_float4(cacc[12], cacc[13], cacc[14], cacc[15]);
    }
    __syncthreads();
    const float4* lp4 = (const float4*)lp;
    const float4 c0 = lp4[tid], c1 = lp4[256 + tid],
                 c2 = lp4[512 + tid], c3 = lp4[768 + tid];
    float4 c4;
    c4.x = (c0.x + c1.x) + (c2.x + c3.x);
    c4.y = (c0.y + c1.y) + (c2.y + c3.y);
    c4.z = (c0.z + c1.z) + (c2.z + c3.z);
    c4.w = (c0.w + c1.w) + (c2.w + c3.w);
    ((float4*)(cpart + ((size_t)((chunk << 6) + b) << 10)))[tid] = c4;
  }
}

// ---------------------------------------------------------------------------
// colsum_wv: wv[b][j] = 2^-10 / sum_s part[s][b][j].  64 blocks x 256 thr.
// ---------------------------------------------------------------------------
__global__ __launch_bounds__(256) void colsum_wv(
    const float* __restrict__ part, float* __restrict__ colwv)
{
  const int b   = blockIdx.x;
  const int tid = threadIdx.x;
  float4 s = {0.f, 0.f, 0.f, 0.f};
  #pragma unroll 8
  for (int c = 0; c < NCHUNK; ++c) {
    const float4 v = ((const float4*)part)[(((size_t)(c << 6) + b) << 8) + tid];
    s.x += v.x; s.y += v.y; s.z += v.z; s.w += v.w;
  }
  float4 w;
  w.x = G10F / s.x; w.y = G10F / s.y; w.z = G10F / s.z; w.w = G10F / s.w;
  ((float4*)colwv)[((size_t)b << 8) + tid] = w;
}

// ---------------------------------------------------------------------------
// final: out = 2^-10 * mean_b sum_j (ccol_j / pcol_j); slab sums inline.
// ---------------------------------------------------------------------------
__global__ __launch_bounds__(256) void final_reduce(
    const float* __restrict__ part, const float* __restrict__ cpart,
    float* __restrict__ out)
{
  const int b   = blockIdx.x;
  const int tid = threadIdx.x;
  float4 p = {0.f, 0.f, 0.f, 0.f}, c = {0.f, 0.f, 0.f, 0.f};
  #pragma unroll 8
  for (int s = 0; s < NCHUNK; ++s) {
    const size_t base = (((size_t)(s << 6) + b) << 8) + tid;
    const float4 pv = ((const float4*)part)[base];
    const float4 cv = ((const float4*)cpart)[base];
    p.x += pv.x; p.y += pv.y; p.z += pv.z; p.w += pv.w;
    c.x += cv.x; c.y += cv.y; c.z += cv.z; c.w += cv.w;
  }
  float r = (c.x / p.x + c.y / p.y) + (c.z / p.z + c.w / p.w);
  #pragma unroll
  for (int m = 1; m <= 32; m <<= 1) r += __shfl_xor(r, m);
  __shared__ float lsf[4];
  if ((tid & 63) == 0) lsf[tid >> 6] = r;
  __syncthreads();
  if (tid == 0)
    atomicAdd(out, (lsf[0] + lsf[1] + lsf[2] + lsf[3]) * (1.0f / 65536.0f));
}

// ---------------------------------------------------------------------------
extern "C" void kernel_launch(void* const* d_in, const int* in_sizes, int n_in,
                              void* d_out, int out_size, void* d_ws, size_t ws_size,
                              hipStream_t stream)
{
  (void)in_sizes; (void)n_in; (void)out_size; (void)ws_size;
  const float* src = (const float*)d_in[0];
  const float* tgt = (const float*)d_in[1];

  char* ws = (char*)d_ws;
  __half* q = (__half*)ws;                                    // 128 MiB
  const size_t QB = (size_t)BATCH * NPT * NPT * sizeof(__half);
  const size_t PART_N = (size_t)NCHUNK * BATCH * NPT;         // 8 MiB
  float* part  = (float*)(ws + QB);
  float* cpart = part + PART_N;                               // 8 MiB
  float* colwv = cpart + PART_N;                              // 256 KB

  hipMemsetAsync(d_out, 0, sizeof(float), stream);

  build_q<<<BATCH * 256, 256, 0, stream>>>(src, tgt, q);

  for (int t = 0; t < 50; ++t) {
    if (t == 0)
      sink_pass<true, false><<<NBLK, 256, 0, stream>>>(q, colwv, part, nullptr);
    else if (t == 49)
      sink_pass<false, true><<<NBLK, 256, 0, stream>>>(q, colwv, part, cpart);
    else
      sink_pass<false, false><<<NBLK, 256, 0, stream>>>(q, colwv, part, nullptr);
    if (t < 49)
      colsum_wv<<<BATCH, 256, 0, stream>>>(part, colwv);
  }

  final_reduce<<<BATCH, 256, 0, stream>>>(part, cpart, (float*)d_out);
}